// Round 15
// baseline (257.648 us; speedup 1.0000x reference)
//
#include <hip/hip_runtime.h>
#include <hip/hip_bf16.h>

#define NN 50000
#define EE 800000
#define FF 128
#define HH 128
#define HID2 64
#define TT 8
#define GG 64
#define NB 196          // CSR buckets of 256 dst nodes
#define NSB 256         // scatter blocks
#define EPB (EE / NSB)  // 3125 edges per scatter block
#define NPAD 50048      // NN padded to 64 (782 * 64)
#define AGRP 782        // aggr 64-node groups

using frag_ab = __attribute__((ext_vector_type(8))) short;  // 8 bf16
using frag_cd = __attribute__((ext_vector_type(4))) float;  // 4 fp32

__device__ inline unsigned short f2bf(float f) {
    union { float f; unsigned u; } v; v.f = f;
    unsigned r = v.u + 0x7fff + ((v.u >> 16) & 1);  // RNE
    return (unsigned short)(r >> 16);
}

// ---- K_FRONT: hist (4 per-wave sub-hists) + W->Wt bf16 + gsum zero --------
__global__ __launch_bounds__(256) void k_front(const int* __restrict__ dst,
                                               const float* __restrict__ W,
                                               int* __restrict__ table,
                                               unsigned short* __restrict__ wt_bf,
                                               float* __restrict__ gsum) {
    __shared__ int cnt[4 * NB];
    int t = threadIdx.x, blk = blockIdx.x;
    int wv = t >> 6;
    if (blk < 64) {                       // W[k][c] -> wt_bf[c][k]
        int gid = blk * 256 + t;
        int c = gid >> 7, k = gid & 127;
        wt_bf[gid] = f2bf(W[k * 128 + c]);
    }
    if (blk >= 64 && blk < 96) {          // zero gsum
        int gid = (blk - 64) * 256 + t;
        gsum[gid] = 0.f;
    }
    for (int i = t; i < 4 * NB; i += 256) cnt[i] = 0;
    __syncthreads();
    int e0 = blk * EPB;
    int* my = cnt + wv * NB;
    for (int e = e0 + t; e < e0 + EPB; e += 256)
        atomicAdd(&my[dst[e] >> 8], 1);
    __syncthreads();
    for (int i = t; i < NB; i += 256)
        table[blk * NB + i] = cnt[i] + cnt[NB + i] + cnt[2 * NB + i] + cnt[3 * NB + i];
}

// ---- KB2a: per-bucket column scan of table (196 blocks) -------------------
__global__ __launch_bounds__(256) void kb2a(int* __restrict__ table,
                                            int* __restrict__ ctot) {
    __shared__ int s[256];
    int t = threadIdx.x, b = blockIdx.x;
    int v = table[t * NB + b];
    s[t] = v;
    __syncthreads();
    for (int off = 1; off < 256; off <<= 1) {
        int a = s[t];
        int w = (t >= off) ? s[t - off] : 0;
        __syncthreads();
        s[t] = a + w;
        __syncthreads();
    }
    table[t * NB + b] = s[t] - v;          // exclusive within column
    if (t == 255) ctot[b] = s[255];
}

// ---- KB2b: exclusive scan of 196 column totals -> bbase -------------------
__global__ __launch_bounds__(256) void kb2b(const int* __restrict__ ctot,
                                            int* __restrict__ bbase) {
    __shared__ int s[256];
    int b = threadIdx.x;
    int v = (b < NB) ? ctot[b] : 0;
    s[b] = v;
    __syncthreads();
    for (int off = 1; off < 256; off <<= 1) {
        int a = s[b];
        int w = (b >= off) ? s[b - off] : 0;
        __syncthreads();
        s[b] = a + w;
        __syncthreads();
    }
    if (b < NB) bbase[b] = s[b] - v;
    if (b == 0) bbase[NB] = EE;
}

// ---- KB3: scatter edges into bucket order (packed dst<<16|src) ------------
__global__ __launch_bounds__(256) void kb3(const int* __restrict__ src,
                                           const int* __restrict__ dst,
                                           const int* __restrict__ table,
                                           const int* __restrict__ bbase,
                                           unsigned* __restrict__ etmp) {
    __shared__ int ofs[NB];
    __shared__ int cur[NB];
    int t = threadIdx.x, blk = blockIdx.x;
    for (int i = t; i < NB; i += 256) {
        ofs[i] = table[blk * NB + i] + bbase[i];
        cur[i] = 0;
    }
    __syncthreads();
    int e0 = blk * EPB;
    for (int e = e0 + t; e < e0 + EPB; e += 256) {
        int d = dst[e];
        int b = d >> 8;
        int r = atomicAdd(&cur[b], 1);
        etmp[ofs[b] + r] = ((unsigned)d << 16) | (unsigned)src[e];
    }
}

// ---- K_CSR: per-bucket  hist -> scan -> row_ptr/dinv -> CSR fill (ushort) -
__global__ __launch_bounds__(256) void k_csr(const unsigned* __restrict__ etmp,
                                             const int* __restrict__ bbase,
                                             int* __restrict__ row_ptr,
                                             float* __restrict__ dinv,
                                             unsigned short* __restrict__ srcs) {
    __shared__ int s[256];
    __shared__ int cur[256];
    int t = threadIdx.x, b = blockIdx.x;
    s[t] = 0;
    __syncthreads();
    int e0 = bbase[b], e1 = bbase[b + 1];
    for (int e = e0 + t; e < e1; e += 256)
        atomicAdd(&s[(etmp[e] >> 16) & 255], 1);
    __syncthreads();
    int v = s[t];
    for (int off = 1; off < 256; off <<= 1) {
        int a = s[t];
        int w = (t >= off) ? s[t - off] : 0;
        __syncthreads();
        s[t] = a + w;
        __syncthreads();
    }
    int excl = s[t] - v + e0;   // e0 == bbase[b] == row_ptr[b*256]
    int node = b * 256 + t;
    if (node < NN) {
        row_ptr[node] = excl;
        dinv[node] = rsqrtf((float)(v + 1));  // +1 self-loop
    }
    if (b == NB - 1 && t == 0) row_ptr[NN] = EE;
    cur[t] = excl;
    __syncthreads();
    for (int e = e0 + t; e < e1; e += 256) {
        unsigned u = etmp[e];
        int slot = atomicAdd(&cur[(u >> 16) & 255], 1);
        srcs[slot] = (unsigned short)(u & 0xffffu);
    }
}

// ---- K4: MFMA GEMM -> slab layout -----------------------------------------
// Quarter q = m>>2 holds row elements idx = (m&3)*8 + nt  <-> feature nt*16+m.
// Slab q base: hsq + q*NPAD*32 ushorts; row = 32 ushorts (64 B).
__global__ __launch_bounds__(256) void k_gemm(const float* __restrict__ x,
                                              const unsigned short* __restrict__ wt_bf,
                                              const float* __restrict__ dinv,
                                              unsigned short* __restrict__ hsq) {
    int tid = threadIdx.x;
    int w = tid >> 6, lane = tid & 63;
    int m = lane & 15, quad = lane >> 4;
    int r0 = blockIdx.x * 64 + w * 16;        // 782 blocks * 64 = NPAD exactly
    int row = r0 + m;
    frag_cd acc[8];
#pragma unroll
    for (int nt = 0; nt < 8; nt++) acc[nt] = frag_cd{0.f, 0.f, 0.f, 0.f};

#pragma unroll
    for (int k0 = 0; k0 < 128; k0 += 32) {
        unsigned short av[8];
        if (row < NN) {
            const float4* p = (const float4*)(x + (size_t)row * 128 + k0 + quad * 8);
            float4 a0 = p[0], a1 = p[1];
            av[0] = f2bf(a0.x); av[1] = f2bf(a0.y); av[2] = f2bf(a0.z); av[3] = f2bf(a0.w);
            av[4] = f2bf(a1.x); av[5] = f2bf(a1.y); av[6] = f2bf(a1.z); av[7] = f2bf(a1.w);
        } else {
#pragma unroll
            for (int j = 0; j < 8; j++) av[j] = 0;
        }
        frag_ab a = *(const frag_ab*)av;
#pragma unroll
        for (int nt = 0; nt < 8; nt++) {
            frag_ab bfr = *(const frag_ab*)(wt_bf + (size_t)(nt * 16 + m) * 128 + k0 + quad * 8);
            acc[nt] = __builtin_amdgcn_mfma_f32_16x16x32_bf16(a, bfr, acc[nt], 0, 0, 0);
        }
    }
    unsigned short* slab = hsq + (size_t)(m >> 2) * ((size_t)NPAD * 32);
    int ji = (m & 3) * 8;
#pragma unroll
    for (int reg = 0; reg < 4; reg++) {
        int gr = r0 + quad * 4 + reg;
        if (gr < NN) {
            float di = dinv[gr];
#pragma unroll
            for (int nt = 0; nt < 8; nt++)
                slab[(size_t)gr * 32 + ji + nt] = f2bf(acc[nt][reg] * di);
        }
    }
}

// ---- K5: edge-parallel CSR-stream gather, XCD-partitioned slabs -----------
// Block = (64-node group, quarter q = blk&3). 64 lane-groups (4 lanes) take
// contiguous edge chunks (uniform trips). Register run-accumulation, LDS
// flush on dst change. Epilogue: self + bias + relu + fused pool.
#define ACC8(u) \
    a0 += __uint_as_float((u).x << 16); a1 += __uint_as_float((u).x & 0xffff0000u); \
    a2 += __uint_as_float((u).y << 16); a3 += __uint_as_float((u).y & 0xffff0000u); \
    a4 += __uint_as_float((u).z << 16); a5 += __uint_as_float((u).z & 0xffff0000u); \
    a6 += __uint_as_float((u).w << 16); a7 += __uint_as_float((u).w & 0xffff0000u);

__global__ __launch_bounds__(256) void k_aggr(const uint4* __restrict__ hsq4,
                                              const int* __restrict__ row_ptr,
                                              const unsigned short* __restrict__ srcs,
                                              const float* __restrict__ dinv,
                                              const float* __restrict__ bias,
                                              const int* __restrict__ batch,
                                              float* __restrict__ gsum) {
    __shared__ int rptr[65];
    __shared__ float gacc[64 * 36];   // 9.2 KB, row stride 36 (bank skew)
    __shared__ float gpool[8 * 32];
    int t = threadIdx.x;
    int q = blockIdx.x & 3;           // feature quarter == XCD partition
    int grp = blockIdx.x >> 2;
    int n0 = grp * 64;
    int lg = t >> 2, j = t & 3;
    if (t <= 64) {
        int nd = n0 + t;
        rptr[t] = row_ptr[nd > NN ? NN : nd];
    }
    for (int i = t; i < 64 * 36; i += 256) gacc[i] = 0.f;
    int lastn = n0 + 63; if (lastn >= NN) lastn = NN - 1;
    int g_first = batch[n0];
    int gspan = batch[lastn] - g_first + 1;
    bool lds_pool = (gspan <= 8);
    int slots = lds_pool ? gspan : 0;
    if (t < slots * 32) gpool[t] = 0.f;
    __syncthreads();

    const uint4* slab4 = hsq4 + (size_t)q * ((size_t)NPAD * 4);
    int e0 = rptr[0], e1 = rptr[64];
    int cnt = e1 - e0;
    int per = (cnt + 63) >> 6;
    int ce = e0 + lg * per;
    int cend = ce + per; if (cend > e1) cend = e1;
    if (ce < cend) {
        int lo = 0, hi = 64;          // find d: rptr[d] <= ce < rptr[d+1]
        while (lo + 1 < hi) {
            int mid = (lo + hi) >> 1;
            if (rptr[mid] <= ce) lo = mid; else hi = mid;
        }
        int d = lo;
        float a0 = 0.f, a1 = 0.f, a2 = 0.f, a3 = 0.f,
              a4 = 0.f, a5 = 0.f, a6 = 0.f, a7 = 0.f;
        for (int e = ce; e < cend; ++e) {
            int s = srcs[e];
            uint4 u = slab4[(size_t)s * 4 + j];
            ACC8(u)
            int nx = e + 1;
            if (nx == rptr[d + 1] || nx == cend) {
                float* gp = &gacc[d * 36 + j * 8];
                atomicAdd(&gp[0], a0); atomicAdd(&gp[1], a1);
                atomicAdd(&gp[2], a2); atomicAdd(&gp[3], a3);
                atomicAdd(&gp[4], a4); atomicAdd(&gp[5], a5);
                atomicAdd(&gp[6], a6); atomicAdd(&gp[7], a7);
                a0 = a1 = a2 = a3 = a4 = a5 = a6 = a7 = 0.f;
                if (nx < cend) {
                    while (rptr[d + 1] <= nx) d++;
                }
            }
        }
    }
    __syncthreads();
    // epilogue: 64 nodes x 32 elems; elem idx <-> feature c = (idx&7)*16 + q*4 + (idx>>3)
    const unsigned short* slab_us = (const unsigned short*)slab4;
    for (int it = t; it < 64 * 32; it += 256) {
        int n = it >> 5, idx = it & 31;
        int node = n0 + n;
        if (node < NN) {
            int c = ((idx & 7) << 4) + q * 4 + (idx >> 3);
            unsigned short sv = slab_us[(size_t)node * 32 + idx];
            float self = __uint_as_float(((unsigned)sv) << 16);
            float v = fmaf(gacc[n * 36 + idx] + self, dinv[node], bias[c]);
            v = fmaxf(v, 0.f);
            int g = batch[node];
            if (lds_pool) atomicAdd(&gpool[(g - g_first) * 32 + idx], v);
            else          atomicAdd(&gsum[g * 128 + c], v);
        }
    }
    __syncthreads();
    if (t < slots * 32) {
        float v = gpool[t];
        int idx = t & 31;
        int c = ((idx & 7) << 4) + q * 4 + (idx >> 3);
        if (v != 0.f)
            atomicAdd(&gsum[(g_first + (t >> 5)) * 128 + c], v);
    }
}

__device__ inline int lbound(const int* __restrict__ a, int n, int key) {
    int lo = 0, hi = n;
    while (lo < hi) {
        int mid = (lo + hi) >> 1;
        if (a[mid] < key) lo = mid + 1;
        else hi = mid;
    }
    return lo;
}

// ---------------- K7: head (mean, fc1 + relu, actor softmax, critic) -------
__global__ __launch_bounds__(64) void k_head(const float* __restrict__ gsum,
                                             const int* __restrict__ batch,
                                             const float* __restrict__ fc1_w,
                                             const float* __restrict__ fc1_b,
                                             const float* __restrict__ actor_w,
                                             const float* __restrict__ actor_b,
                                             const float* __restrict__ critic_w,
                                             const float* __restrict__ critic_b,
                                             float* __restrict__ out) {
    __shared__ float gs[128];
    __shared__ float zs[64];
    __shared__ float ls[8], es[8];
    int g = blockIdx.x, t = threadIdx.x;
    int lo = lbound(batch, NN, g), hi = lbound(batch, NN, g + 1);
    float invc = 1.f / fmaxf((float)(hi - lo), 1.f);
    gs[t] = gsum[g * 128 + t] * invc;
    gs[t + 64] = gsum[g * 128 + 64 + t] * invc;
    __syncthreads();
    float z = fc1_b[t];
    for (int k = 0; k < 128; k++) z = fmaf(gs[k], fc1_w[k * 64 + t], z);
    zs[t] = fmaxf(z, 0.f);
    __syncthreads();
    if (t < 8) {
        float l = actor_b[t];
        for (int k = 0; k < 64; k++) l = fmaf(zs[k], actor_w[k * 8 + t], l);
        ls[t] = l;
    }
    __syncthreads();
    if (t < 8) {
        float m = ls[0];
#pragma unroll
        for (int j = 1; j < 8; j++) m = fmaxf(m, ls[j]);
        es[t] = expf(ls[t] - m);
    }
    __syncthreads();
    if (t < 8) {
        float ssum = 0.f;
#pragma unroll
        for (int j = 0; j < 8; j++) ssum += es[j];
        out[g * 8 + t] = es[t] / ssum;
    }
    if (t == 32) {
        float v = critic_b[0];
        for (int k = 0; k < 64; k++) v = fmaf(zs[k], critic_w[k], v);
        out[GG * TT + g] = v;
    }
}

extern "C" void kernel_launch(void* const* d_in, const int* in_sizes, int n_in,
                              void* d_out, int out_size, void* d_ws, size_t ws_size,
                              hipStream_t stream) {
    const float* x        = (const float*)d_in[0];
    const int*   ei       = (const int*)d_in[1];
    const int*   batch    = (const int*)d_in[2];
    const float* W        = (const float*)d_in[3];
    const float* b        = (const float*)d_in[4];
    const float* fc1_w    = (const float*)d_in[5];
    const float* fc1_b    = (const float*)d_in[6];
    const float* actor_w  = (const float*)d_in[7];
    const float* actor_b  = (const float*)d_in[8];
    const float* critic_w = (const float*)d_in[9];
    const float* critic_b = (const float*)d_in[10];
    float* out = (float*)d_out;

    char* ws = (char*)d_ws;
    size_t off = 0;
    unsigned short* hsq   = (unsigned short*)(ws + off); off += (size_t)NPAD * 128 * 2 + 64; // 12.8 MB
    unsigned short* wt_bf = (unsigned short*)(ws + off); off += (size_t)128 * 128 * 2;       // 32 KB
    float* dinv      = (float*)(ws + off);    off += (size_t)NN * 4;
    int*   row_ptr   = (int*)(ws + off);      off += (size_t)(NN + 1) * 4 + 12;
    unsigned short* srcs = (unsigned short*)(ws + off); off += (size_t)EE * 2 + 32;  // 1.6 MB
    unsigned* etmp   = (unsigned*)(ws + off); off += (size_t)EE * 4;       // 3.2 MB
    int*   table     = (int*)(ws + off);      off += (size_t)NSB * NB * 4; // 200 KB
    int*   bbase     = (int*)(ws + off);      off += (size_t)(NB + 1) * 4 + 12;
    int*   ctot      = (int*)(ws + off);      off += (size_t)NB * 4 + 16;
    float* gsum      = (float*)(ws + off);    off += (size_t)GG * HH * 4;

    const int* src = ei;        // edge_index[0]
    const int* dst = ei + EE;   // edge_index[1]

    k_front<<<NSB, 256, 0, stream>>>(dst, W, table, wt_bf, gsum);
    kb2a<<<NB, 256, 0, stream>>>(table, ctot);
    kb2b<<<1, 256, 0, stream>>>(ctot, bbase);
    kb3<<<NSB, 256, 0, stream>>>(src, dst, table, bbase, etmp);
    k_csr<<<NB, 256, 0, stream>>>(etmp, bbase, row_ptr, dinv, srcs);
    k_gemm<<<NPAD / 64, 256, 0, stream>>>(x, wt_bf, dinv, hsq);
    k_aggr<<<AGRP * 4, 256, 0, stream>>>((const uint4*)hsq, row_ptr, srcs,
                                         dinv, b, batch, gsum);
    k_head<<<GG, 64, 0, stream>>>(gsum, batch, fc1_w, fc1_b, actor_w, actor_b,
                                  critic_w, critic_b, out);
}